// Round 19
// baseline (3674.005 us; speedup 1.0000x reference)
//
#include <hip/hip_runtime.h>
#include <hip/hip_bf16.h>

// LSTM: T=512, B=64, H=512, L=2.  inputs: x[T,B,H] f32, Wh[L,H,4H], Wx[L,H,4H], bh[L,4H]
// out = concat(out[T,B,H], h_fin[L,B,H], c_fin[L,B,H]) f32.
//
// R19 = R18 (1649us: tagged 8B records, relaxed sc1, data IS the flag,
// split MFMA chains, fast tanh) + ROLE-SPLIT STAGING:
//   threads   0..255  : gates + publish ONLY (no staging load)
//   threads 256..511  : stage cross tile (xq for L0 / h0[s-1] slack for L1)
//   threads 512..1023 : stage self-h tile (critical edge)
// Stagers fall through the gate phase at bar2 and immediately probe the
// NEXT stage's h records - discovery overlaps gates+publish instead of
// running serially after them (R18's gate threads paid probe latency on
// the critical path). Protocol/tags/ring/throttle semantics unchanged.
// Each stager's record group comes from ONE producer strip (joint retry).

#define TSEQ 512
#define BATCH 64
#define HID 512
#define H4 2048
#define BH (BATCH * HID)
#define DEPTH 8
#define QR 16            // batch rows per quad
#define NSTRIP 16        // strips per (layer,quad); 32 cols each
#define RPR 256          // records per row (HID/2)
#define BRPR (BATCH * RPR)

typedef short bf16x8 __attribute__((ext_vector_type(8)));
typedef float f32x4 __attribute__((ext_vector_type(4)));
typedef float f32x2 __attribute__((ext_vector_type(2)));
typedef unsigned long long u64;
typedef u64 u64x2 __attribute__((ext_vector_type(2)));

__device__ __forceinline__ ushort f32_to_bf16(float f) {
    unsigned u = __builtin_bit_cast(unsigned, f);
    u += 0x7FFFu + ((u >> 16) & 1u);   // round-to-nearest-even
    return (ushort)(u >> 16);
}

__device__ __forceinline__ float tanh_fast(float x) {
    return 1.f - 2.f / (1.f + __expf(2.f * x));   // exact at +-inf, ~1e-7 rel err
}

__device__ __forceinline__ bf16x8 unpack_recs(u64x2 a, u64x2 b) {
    union { unsigned u[4]; bf16x8 v; } r;
    r.u[0] = (unsigned)a.x; r.u[1] = (unsigned)a.y;
    r.u[2] = (unsigned)b.x; r.u[3] = (unsigned)b.y;
    return r.v;
}
__device__ __forceinline__ bool tags4(u64x2 a, u64x2 b, unsigned tag) {
    return (unsigned)(a.x >> 32) == tag && (unsigned)(a.y >> 32) == tag &&
           (unsigned)(b.x >> 32) == tag && (unsigned)(b.y >> 32) == tag;
}

// ---- convert x f32 -> bf16 (vectorized) ----
__global__ __launch_bounds__(256) void convert_x(const float* __restrict__ x,
                                                 ushort* __restrict__ xq) {
    const int n4 = (TSEQ * BATCH * HID) / 4;
    int stride = gridDim.x * blockDim.x;
    for (int i = blockIdx.x * blockDim.x + threadIdx.x; i < n4; i += stride) {
        float4 v = ((const float4*)x)[i];
        ushort4 o;
        o.x = f32_to_bf16(v.x);
        o.y = f32_to_bf16(v.y);
        o.z = f32_to_bf16(v.z);
        o.w = f32_to_bf16(v.w);
        ((ushort4*)xq)[i] = o;
    }
}

// ---- transpose+convert weights: WT[m][n][k] = W[k][n], m: 0=Wx0 1=Wh0 2=Wx1 3=Wh1 ----
__global__ __launch_bounds__(256) void transpose_w(const float* __restrict__ Wh,
                                                   const float* __restrict__ Wx,
                                                   ushort* __restrict__ WT) {
    int bid = blockIdx.x;            // 4 * 8 * 32 = 1024 blocks
    int m  = bid >> 8;               // 0..3
    int kt = (bid >> 5) & 7;         // k tile (64)
    int nt = bid & 31;               // n tile (64)
    const float* src = ((m & 1) ? Wh : Wx) + (size_t)(m >> 1) * (HID * H4);

    __shared__ float tile[64][65];
    int c  = threadIdx.x & 63;
    int r0 = (threadIdx.x >> 6) * 16;
    for (int i = 0; i < 16; ++i) {
        int r = r0 + i;
        tile[r][c] = src[(size_t)(kt * 64 + r) * H4 + nt * 64 + c];
    }
    __syncthreads();
    int k  = threadIdx.x & 63;
    int n0 = (threadIdx.x >> 6) * 16;
    for (int i = 0; i < 16; ++i) {
        int n = n0 + i;
        WT[(size_t)m * (H4 * HID) + (size_t)(nt * 64 + n) * HID + kt * 64 + k] =
            f32_to_bf16(tile[k][n]);
    }
}

// ---- persistent LSTM kernel: 128 WGs x 1024 threads ----
__global__ __launch_bounds__(1024, 4) void lstm_persistent(
    const ushort* __restrict__ WT,   // [4][2048][512] bf16 (N-major, K contiguous)
    const ushort* __restrict__ xq,   // [512][64][512] bf16
    const float*  __restrict__ bh,   // [2][2048]
    u64*   __restrict__ h0T,         // [DEPTH][64][256] tagged records
    u64*   __restrict__ h1T,         // [DEPTH][64][256]
    float* __restrict__ out,         // d_out
    int*   __restrict__ f1prog)      // [4][16] L1 progress (throttle), zeroed
{
    const int wg    = blockIdx.x;        // 0..127
    const int layer = wg >> 6;
    const int quad  = (wg >> 4) & 3;
    const int strip = wg & 15;           // 32-column strip
    const int j0    = strip * 32;
    const int tid   = threadIdx.x;
    const int wave  = tid >> 6;          // 0..15
    const int lane  = tid & 63;
    const int g     = wave & 3;          // gate
    const int ch    = (wave >> 2) & 1;   // col-tile half (16 cols)
    const int kh    = wave >> 3;         // K half (0..1)
    const int lo    = lane & 15;
    const int hi    = lane >> 4;

    int* myprog = &f1prog[quad * NSTRIP + strip];   // only L1 publishes

    // weight fragment base pointers (gemm_bt layout, k contiguous-8/lane)
    const ushort* bx = WT + (size_t)(layer * 2 + 0) * (H4 * HID)
                     + (size_t)(g * 512 + j0 + ch * 16 + lo) * HID + kh * 256 + hi * 8;
    const ushort* bw = WT + (size_t)(layer * 2 + 1) * (H4 * HID)
                     + (size_t)(g * 512 + j0 + ch * 16 + lo) * HID + kh * 256 + hi * 8;
    bf16x8 wx[8], wh[8];
#pragma unroll
    for (int kk = 0; kk < 8; ++kk) {
        wx[kk] = *(const bf16x8*)(bx + kk * 32);
        wh[kk] = *(const bf16x8*)(bw + kk * 32);
    }
#pragma unroll
    for (int kk = 0; kk < 8; ++kk) {
        asm volatile("" : "+v"(wx[kk]));
        asm volatile("" : "+v"(wh[kk]));
    }

    // gate-phase mapping (threads 0..255): row = tid>>4, cols cp,cp+1 (0..31)
    const int grow = tid >> 4;
    const int cp   = (tid & 15) * 2;
    f32x2 bias2[4];
#pragma unroll
    for (int gg = 0; gg < 4; ++gg)
        bias2[gg] = *(const f32x2*)&bh[layer * H4 + gg * 512 + j0 + cp];
    f32x2 creg = (f32x2)(0.f);

    __shared__ __align__(16) ushort ldsA[2][QR * HID];      // 32 KB: cross, self
    __shared__ __align__(16) float  lds_g[4][2][QR][34];    // padded (32+2)

    // ---- staging roles ----
    // self stagers: tid 512..1023 -> 8 records (16 bf16) each, one producer strip
    const int sj   = tid - 512;
    const int srow = (sj >> 5) & 15;
    const int scs  = sj & 31;
    const int roffS = (quad * QR + srow) * RPR + scs * 8;
    const int lS0 = (srow << 10) + (((scs * 2 + 0) << 4) ^ ((srow & 15) << 4));
    const int lS1 = (srow << 10) + (((scs * 2 + 1) << 4) ^ ((srow & 15) << 4));
    // cross stagers: tid 256..511 -> 16 records (32 bf16) each, one producer strip
    const int cj   = tid - 256;
    const int crow = (cj >> 4) & 15;
    const int ccs  = cj & 15;
    const int roffC = (quad * QR + crow) * RPR + ccs * 16;
    const int goffC = (quad * QR + crow) * HID + ccs * 32;   // bf16 elems (L0 xq)
    int lC[4];
#pragma unroll
    for (int k = 0; k < 4; ++k)
        lC[k] = (crow << 10) + (((ccs * 4 + k) << 4) ^ ((crow & 15) << 4));

    const bf16x8 zero8 = {0, 0, 0, 0, 0, 0, 0, 0};

    for (int s = 0; s <= TSEQ; ++s) {
        const int t = s - layer;
        const bool active = (t >= 0 && t < TSEQ);

        if (active) {
            if (tid >= 512) {
                // ---- self-h tile stagers (critical edge) ----
                bf16x8 w0, w1;
                const bool selfzero = layer ? (s == 1) : (s == 0);
                if (selfzero) {
                    w0 = zero8; w1 = zero8;
                } else {
                    const u64* p = (layer ? h1T : h0T)
                        + (size_t)((layer ? (s - 2) : (s - 1)) & 7) * BRPR + roffS;
                    const unsigned tag = (unsigned)(layer ? (s - 1) : s);
                    u64x2 a, b, c, d;
                    for (;;) {
                        asm volatile(
                            "global_load_dwordx4 %0, %4, off sc1\n\t"
                            "global_load_dwordx4 %1, %5, off sc1\n\t"
                            "global_load_dwordx4 %2, %6, off sc1\n\t"
                            "global_load_dwordx4 %3, %7, off sc1\n\t"
                            "s_waitcnt vmcnt(0)"
                            : "=&v"(a), "=&v"(b), "=&v"(c), "=&v"(d)
                            : "v"(p), "v"(p + 2), "v"(p + 4), "v"(p + 6) : "memory");
                        if (tags4(a, b, tag) && tags4(c, d, tag)) break;
                        __builtin_amdgcn_s_sleep(1);
                    }
                    w0 = unpack_recs(a, b);
                    w1 = unpack_recs(c, d);
                }
                *(bf16x8*)((char*)&ldsA[1][0] + lS0) = w0;
                *(bf16x8*)((char*)&ldsA[1][0] + lS1) = w1;
            } else if (tid >= 256) {
                // ---- cross tile stagers (xq for L0; h0[s-1] slack for L1) ----
                bf16x8 u0, u1, u2, u3;
                if (layer == 0) {
                    const ushort* X = xq + (size_t)t * BH + goffC;
                    u0 = *(const bf16x8*)(X + 0);
                    u1 = *(const bf16x8*)(X + 8);
                    u2 = *(const bf16x8*)(X + 16);
                    u3 = *(const bf16x8*)(X + 24);
                } else {
                    const u64* p = h0T + (size_t)((s - 1) & 7) * BRPR + roffC;
                    const unsigned tag = (unsigned)s;
                    u64x2 a, b, c, d, e, f, g2, h2;
                    for (;;) {
                        asm volatile(
                            "global_load_dwordx4 %0, %8, off sc1\n\t"
                            "global_load_dwordx4 %1, %9, off sc1\n\t"
                            "global_load_dwordx4 %2, %10, off sc1\n\t"
                            "global_load_dwordx4 %3, %11, off sc1\n\t"
                            "global_load_dwordx4 %4, %12, off sc1\n\t"
                            "global_load_dwordx4 %5, %13, off sc1\n\t"
                            "global_load_dwordx4 %6, %14, off sc1\n\t"
                            "global_load_dwordx4 %7, %15, off sc1\n\t"
                            "s_waitcnt vmcnt(0)"
                            : "=&v"(a), "=&v"(b), "=&v"(c), "=&v"(d),
                              "=&v"(e), "=&v"(f), "=&v"(g2), "=&v"(h2)
                            : "v"(p), "v"(p + 2), "v"(p + 4), "v"(p + 6),
                              "v"(p + 8), "v"(p + 10), "v"(p + 12), "v"(p + 14)
                            : "memory");
                        if (tags4(a, b, tag) && tags4(c, d, tag) &&
                            tags4(e, f, tag) && tags4(g2, h2, tag)) break;
                        __builtin_amdgcn_s_sleep(1);
                    }
                    u0 = unpack_recs(a, b);
                    u1 = unpack_recs(c, d);
                    u2 = unpack_recs(e, f);
                    u3 = unpack_recs(g2, h2);
                }
                *(bf16x8*)((char*)&ldsA[0][0] + lC[0]) = u0;
                *(bf16x8*)((char*)&ldsA[0][0] + lC[1]) = u1;
                *(bf16x8*)((char*)&ldsA[0][0] + lC[2]) = u2;
                *(bf16x8*)((char*)&ldsA[0][0] + lC[3]) = u3;
            } else {
                // ---- gate threads: only the L0 ring-overwrite throttle ----
                if (layer == 0 && s >= 6 && tid < NSTRIP) {
                    const int* f = &f1prog[quad * NSTRIP + tid];
                    while (__hip_atomic_load(f, __ATOMIC_RELAXED,
                                             __HIP_MEMORY_SCOPE_AGENT) < s - 6)
                        __builtin_amdgcn_s_sleep(1);
                }
            }
            __syncthreads();                         // bar1: tiles staged

            // L1 progress publish (throttle only; no drain needed)
            if (layer == 1 && tid == 0)
                __hip_atomic_store(myprog, s, __ATOMIC_RELAXED,
                                   __HIP_MEMORY_SCOPE_AGENT);

            // MFMA: wave (g, ch, kh); two independent 8-deep chains
            f32x4 acc0 = (f32x4)(0.f), acc1 = (f32x4)(0.f);
#pragma unroll
            for (int kk = 0; kk < 8; ++kk) {
                const int kb2 = kh * 512 + kk * 64 + hi * 16;        // byte offset in row
                const int ad  = ((lo << 10) + kb2) ^ ((lo & 15) << 4);
                bf16x8 a1 = *(const bf16x8*)((char*)&ldsA[0][0] + ad);
                bf16x8 a2 = *(const bf16x8*)((char*)&ldsA[1][0] + ad);
                acc0 = __builtin_amdgcn_mfma_f32_16x16x32_bf16(a1, wx[kk], acc0, 0, 0, 0);
                acc1 = __builtin_amdgcn_mfma_f32_16x16x32_bf16(a2, wh[kk], acc1, 0, 0, 0);
            }
            f32x4 acc = acc0 + acc1;
            // C/D layout: col = lane&15, row = (lane>>4)*4 + r
#pragma unroll
            for (int r = 0; r < 4; ++r)
                lds_g[g][kh][hi * 4 + r][ch * 16 + lo] = acc[r];
            __syncthreads();                         // bar2: partials ready

            // gates (threads 0..255): 2 cells per thread; publish tagged record
            if (tid < 256) {
                f32x2 gi = *(const f32x2*)&lds_g[0][0][grow][cp]
                         + *(const f32x2*)&lds_g[0][1][grow][cp] + bias2[0];
                f32x2 gf = *(const f32x2*)&lds_g[1][0][grow][cp]
                         + *(const f32x2*)&lds_g[1][1][grow][cp] + bias2[1];
                f32x2 gg = *(const f32x2*)&lds_g[2][0][grow][cp]
                         + *(const f32x2*)&lds_g[2][1][grow][cp] + bias2[2];
                f32x2 go = *(const f32x2*)&lds_g[3][0][grow][cp]
                         + *(const f32x2*)&lds_g[3][1][grow][cp] + bias2[3];
                f32x2 cn, hn;
#pragma unroll
                for (int q = 0; q < 2; ++q) {
                    float si = 1.f / (1.f + __expf(-gi[q]));
                    float sf = 1.f / (1.f + __expf(-gf[q]));
                    float so = 1.f / (1.f + __expf(-go[q]));
                    float tg = tanh_fast(gg[q]);
                    cn[q] = sf * creg[q] + si * tg;
                    hn[q] = so * tanh_fast(cn[q]);
                }
                creg = cn;

                unsigned hp = (unsigned)f32_to_bf16(hn[0])
                            | ((unsigned)f32_to_bf16(hn[1]) << 16);
                u64 rec = (u64)hp | ((u64)(unsigned)(t + 1) << 32);
                u64* hw = ((layer == 0) ? h0T : h1T)
                        + (size_t)(t & 7) * BRPR
                        + (size_t)(quad * QR + grow) * RPR + ((j0 + cp) >> 1);
                __hip_atomic_store(hw, rec, __ATOMIC_RELAXED,
                                   __HIP_MEMORY_SCOPE_AGENT);

                // out / finals (plain stores, off the handshake path)
                const int hoff = (quad * QR + grow) * HID + j0 + cp;
                if (layer == 1)
                    *(f32x2*)&out[(size_t)t * BH + hoff] = hn;
                if (t == TSEQ - 1) {
                    size_t base = (size_t)TSEQ * BH + (size_t)layer * BH + hoff;
                    *(f32x2*)&out[base] = hn;                       // h_fin
                    *(f32x2*)&out[base + 2 * (size_t)BH] = cn;      // c_fin
                }
            }
        } else {
            // inactive stage: L1 keeps progress monotone for the throttle
            if (layer == 1 && tid == 0)
                __hip_atomic_store(myprog, s, __ATOMIC_RELAXED,
                                   __HIP_MEMORY_SCOPE_AGENT);
            __syncthreads();
        }
    }
}

extern "C" void kernel_launch(void* const* d_in, const int* in_sizes, int n_in,
                              void* d_out, int out_size, void* d_ws, size_t ws_size,
                              hipStream_t stream) {
    const float* x  = (const float*)d_in[0];
    const float* Wh = (const float*)d_in[1];
    const float* Wx = (const float*)d_in[2];
    const float* bh = (const float*)d_in[3];
    float* out = (float*)d_out;

    char* ws = (char*)d_ws;
    // layout: WT 8MB | xq 32MB | h0T 1MB | h1T 1MB | f1prog  (~42MB total)
    ushort* WT = (ushort*)ws;
    ushort* xq = (ushort*)(ws + ((size_t)8 << 20));
    char* state = ws + ((size_t)8 << 20) + ((size_t)32 << 20);
    u64* h0T = (u64*)state;                                // [8][64][256] u64
    u64* h1T = h0T + (size_t)DEPTH * BRPR;
    int* f1prog = (int*)(h1T + (size_t)DEPTH * BRPR);      // [4][16]
    size_t clear_bytes = (size_t)2 * DEPTH * BRPR * sizeof(u64)
                       + 64 * sizeof(int);

    hipMemsetAsync(state, 0, clear_bytes, stream);  // zero tags + progress flags
    convert_x<<<2048, 256, 0, stream>>>(x, xq);
    transpose_w<<<1024, 256, 0, stream>>>(Wh, Wx, WT);
    lstm_persistent<<<128, 1024, 0, stream>>>(WT, xq, bh, h0T, h1T, out, f1prog);
}

// Round 20
// 1650.231 us; speedup vs baseline: 2.2264x; 2.2264x over previous
//
#include <hip/hip_runtime.h>
#include <hip/hip_bf16.h>

// LSTM: T=512, B=64, H=512, L=2.  inputs: x[T,B,H] f32, Wh[L,H,4H], Wx[L,H,4H], bh[L,4H]
// out = concat(out[T,B,H], h_fin[L,B,H], c_fin[L,B,H]) f32.
//
// R20 = EXACT R18 restore (session best: 1649us).
// Architecture: persistent kernel, 128 WGs = 2 layers x 4 quads x 16 strips,
// 1024 threads. Cross-WG h exchange via TAGGED 8B records [2 bf16 | tag=t+1]
// with relaxed sc1 (MALL-coherent, never flushes L2) atomics - the data IS
// the flag; consumers retry-load until tags match (serialized per-pair
// retries: R14/R15's batched/overlapped variants regressed via laggard
// amplification). L1 skew t=s-1; L0 ring-throttle on L1 progress (slack 6);
// (row&15) XOR LDS swizzle; two independent 8-deep MFMA chains; fast tanh.
// Structural rewrites tried and regressed: phase-split (R7), XCD-local
// (R8 deadlock), wave-specialized staging (R9), batched retry (R14), split
// retry (R15), layer fusion (R16), role-split staging (R19). The remaining
// ~3.2us/stage period is fabric-latency-bound (publish->discover MALL RT +
// staging RT + bars + MFMA + gates), at 6.7% HBM / 6.8% MFMA util.

#define TSEQ 512
#define BATCH 64
#define HID 512
#define H4 2048
#define BH (BATCH * HID)
#define DEPTH 8
#define QR 16            // batch rows per quad
#define NSTRIP 16        // strips per (layer,quad); 32 cols each
#define RPR 256          // records per row (HID/2)

typedef short bf16x8 __attribute__((ext_vector_type(8)));
typedef float f32x4 __attribute__((ext_vector_type(4)));
typedef float f32x2 __attribute__((ext_vector_type(2)));
typedef unsigned long long u64;
typedef u64 u64x2 __attribute__((ext_vector_type(2)));

__device__ __forceinline__ ushort f32_to_bf16(float f) {
    unsigned u = __builtin_bit_cast(unsigned, f);
    u += 0x7FFFu + ((u >> 16) & 1u);   // round-to-nearest-even
    return (ushort)(u >> 16);
}

__device__ __forceinline__ float tanh_fast(float x) {
    return 1.f - 2.f / (1.f + __expf(2.f * x));   // exact at +-inf, ~1e-7 rel err
}

// retry-load 4 tagged records (32B) until all tags == tag; returns 8 bf16
__device__ __forceinline__ bf16x8 load_tagged(const u64* p, unsigned tag) {
    u64x2 a, b;
    for (;;) {
        asm volatile("global_load_dwordx4 %0, %2, off sc1\n\t"
                     "global_load_dwordx4 %1, %3, off sc1\n\t"
                     "s_waitcnt vmcnt(0)"
                     : "=&v"(a), "=&v"(b) : "v"(p), "v"(p + 2) : "memory");
        if ((unsigned)(a.x >> 32) == tag && (unsigned)(a.y >> 32) == tag &&
            (unsigned)(b.x >> 32) == tag && (unsigned)(b.y >> 32) == tag) break;
        __builtin_amdgcn_s_sleep(1);
    }
    union { unsigned u[4]; bf16x8 v; } r;
    r.u[0] = (unsigned)a.x; r.u[1] = (unsigned)a.y;
    r.u[2] = (unsigned)b.x; r.u[3] = (unsigned)b.y;
    return r.v;
}

// ---- convert x f32 -> bf16 (vectorized) ----
__global__ __launch_bounds__(256) void convert_x(const float* __restrict__ x,
                                                 ushort* __restrict__ xq) {
    const int n4 = (TSEQ * BATCH * HID) / 4;
    int stride = gridDim.x * blockDim.x;
    for (int i = blockIdx.x * blockDim.x + threadIdx.x; i < n4; i += stride) {
        float4 v = ((const float4*)x)[i];
        ushort4 o;
        o.x = f32_to_bf16(v.x);
        o.y = f32_to_bf16(v.y);
        o.z = f32_to_bf16(v.z);
        o.w = f32_to_bf16(v.w);
        ((ushort4*)xq)[i] = o;
    }
}

// ---- transpose+convert weights: WT[m][n][k] = W[k][n], m: 0=Wx0 1=Wh0 2=Wx1 3=Wh1 ----
__global__ __launch_bounds__(256) void transpose_w(const float* __restrict__ Wh,
                                                   const float* __restrict__ Wx,
                                                   ushort* __restrict__ WT) {
    int bid = blockIdx.x;            // 4 * 8 * 32 = 1024 blocks
    int m  = bid >> 8;               // 0..3
    int kt = (bid >> 5) & 7;         // k tile (64)
    int nt = bid & 31;               // n tile (64)
    const float* src = ((m & 1) ? Wh : Wx) + (size_t)(m >> 1) * (HID * H4);

    __shared__ float tile[64][65];
    int c  = threadIdx.x & 63;
    int r0 = (threadIdx.x >> 6) * 16;
    for (int i = 0; i < 16; ++i) {
        int r = r0 + i;
        tile[r][c] = src[(size_t)(kt * 64 + r) * H4 + nt * 64 + c];
    }
    __syncthreads();
    int k  = threadIdx.x & 63;
    int n0 = (threadIdx.x >> 6) * 16;
    for (int i = 0; i < 16; ++i) {
        int n = n0 + i;
        WT[(size_t)m * (H4 * HID) + (size_t)(nt * 64 + n) * HID + kt * 64 + k] =
            f32_to_bf16(tile[k][n]);
    }
}

// ---- persistent LSTM kernel: 128 WGs x 1024 threads ----
__global__ __launch_bounds__(1024, 4) void lstm_persistent(
    const ushort* __restrict__ WT,   // [4][2048][512] bf16 (N-major, K contiguous)
    const ushort* __restrict__ xq,   // [512][64][512] bf16
    const float*  __restrict__ bh,   // [2][2048]
    u64*   __restrict__ h0T,         // [DEPTH][64][256] tagged records
    u64*   __restrict__ h1T,         // [DEPTH][64][256]
    float* __restrict__ out,         // d_out
    int*   __restrict__ f1prog)      // [4][16] L1 progress (throttle), zeroed
{
    const int wg    = blockIdx.x;        // 0..127
    const int layer = wg >> 6;
    const int quad  = (wg >> 4) & 3;
    const int strip = wg & 15;           // 32-column strip
    const int j0    = strip * 32;
    const int tid   = threadIdx.x;
    const int wave  = tid >> 6;          // 0..15
    const int lane  = tid & 63;
    const int g     = wave & 3;          // gate
    const int ch    = (wave >> 2) & 1;   // col-tile half (16 cols)
    const int kh    = wave >> 3;         // K half (0..1)
    const int lo    = lane & 15;
    const int hi    = lane >> 4;

    int* myprog = &f1prog[quad * NSTRIP + strip];   // only L1 publishes

    // weight fragment base pointers (gemm_bt layout, k contiguous-8/lane)
    const ushort* bx = WT + (size_t)(layer * 2 + 0) * (H4 * HID)
                     + (size_t)(g * 512 + j0 + ch * 16 + lo) * HID + kh * 256 + hi * 8;
    const ushort* bw = WT + (size_t)(layer * 2 + 1) * (H4 * HID)
                     + (size_t)(g * 512 + j0 + ch * 16 + lo) * HID + kh * 256 + hi * 8;
    bf16x8 wx[8], wh[8];
#pragma unroll
    for (int kk = 0; kk < 8; ++kk) {
        wx[kk] = *(const bf16x8*)(bx + kk * 32);
        wh[kk] = *(const bf16x8*)(bw + kk * 32);
    }
#pragma unroll
    for (int kk = 0; kk < 8; ++kk) {
        asm volatile("" : "+v"(wx[kk]));
        asm volatile("" : "+v"(wh[kk]));
    }

    // gate-phase mapping (threads 0..255): row = tid>>4 (0..15), cols cp,cp+1 (0..31)
    const int grow = tid >> 4;
    const int cp   = (tid & 15) * 2;
    f32x2 bias2[4];
#pragma unroll
    for (int gg = 0; gg < 4; ++gg)
        bias2[gg] = *(const f32x2*)&bh[layer * H4 + gg * 512 + j0 + cp];
    f32x2 creg = (f32x2)(0.f);

    __shared__ __align__(16) ushort ldsA[2][QR * HID];      // 32 KB: A1, A2 tiles
    __shared__ __align__(16) float  lds_g[4][2][QR][34];    // padded (32+2)

    // staging: 1024 threads, 8 bf16 per matrix: row = tid>>6, kba = tid&63
    const int row  = tid >> 6;             // 0..15
    const int kba  = tid & 63;
    const int goff  = (quad * QR + row) * HID + kba * 8;               // bf16 elems
    const int roff  = (quad * QR + row) * RPR + kba * 4;               // records
    const int laddr = ((row << 10) + (kba << 4)) ^ ((row & 15) << 4);
    const bf16x8 zero8 = {0, 0, 0, 0, 0, 0, 0, 0};

    for (int s = 0; s <= TSEQ; ++s) {
        const int t = s - layer;
        const bool active = (t >= 0 && t < TSEQ);

        if (active) {
            bf16x8 v0, v1;
            if (layer == 0) {
                // xq static: plain cached load (L2-hot)
                v0 = *(const bf16x8*)(xq + (size_t)t * BH + goff);
                // ring-overwrite throttle: L1 must be past s-6 (slack; rarely spins)
                if (s >= 6 && tid < NSTRIP) {
                    const int* f = &f1prog[quad * NSTRIP + tid];
                    while (__hip_atomic_load(f, __ATOMIC_RELAXED,
                                             __HIP_MEMORY_SCOPE_AGENT) < s - 6)
                        __builtin_amdgcn_s_sleep(1);
                }
                // self-recurrence h0[t-1]: tagged retry-load (tag = t)
                v1 = (t == 0) ? zero8
                              : load_tagged(h0T + (size_t)((t - 1) & 7) * (BATCH * RPR)
                                            + roff, (unsigned)t);
            } else {
                // h0[t]: tag t+1 (one stage of pipeline slack via skew)
                v0 = load_tagged(h0T + (size_t)(t & 7) * (BATCH * RPR) + roff,
                                 (unsigned)(t + 1));
                // self-recurrence h1[t-1]: tag t
                v1 = (t == 0) ? zero8
                              : load_tagged(h1T + (size_t)((t - 1) & 7) * (BATCH * RPR)
                                            + roff, (unsigned)t);
            }
            __builtin_amdgcn_sched_barrier(0);
            *(bf16x8*)((char*)&ldsA[0][0] + laddr) = v0;
            *(bf16x8*)((char*)&ldsA[1][0] + laddr) = v1;
            __syncthreads();                         // bar1: tiles staged

            // L1 progress publish (throttle only; no drain needed)
            if (layer == 1 && tid == 0)
                __hip_atomic_store(myprog, s, __ATOMIC_RELAXED,
                                   __HIP_MEMORY_SCOPE_AGENT);

            // MFMA: wave (g, ch, kh); TWO independent 8-deep chains
            f32x4 acc0 = (f32x4)(0.f), acc1 = (f32x4)(0.f);
#pragma unroll
            for (int kk = 0; kk < 8; ++kk) {
                const int kb2 = kh * 512 + kk * 64 + hi * 16;        // byte offset in row
                const int ad  = ((lo << 10) + kb2) ^ ((lo & 15) << 4);
                bf16x8 a1 = *(const bf16x8*)((char*)&ldsA[0][0] + ad);
                bf16x8 a2 = *(const bf16x8*)((char*)&ldsA[1][0] + ad);
                acc0 = __builtin_amdgcn_mfma_f32_16x16x32_bf16(a1, wx[kk], acc0, 0, 0, 0);
                acc1 = __builtin_amdgcn_mfma_f32_16x16x32_bf16(a2, wh[kk], acc1, 0, 0, 0);
            }
            f32x4 acc = acc0 + acc1;
            // C/D layout: col = lane&15, row = (lane>>4)*4 + r
#pragma unroll
            for (int r = 0; r < 4; ++r)
                lds_g[g][kh][hi * 4 + r][ch * 16 + lo] = acc[r];
            __syncthreads();                         // bar2: partials ready

            // gates (threads 0..255): 2 cells per thread; publish tagged record
            if (tid < 256) {
                f32x2 gi = *(const f32x2*)&lds_g[0][0][grow][cp]
                         + *(const f32x2*)&lds_g[0][1][grow][cp] + bias2[0];
                f32x2 gf = *(const f32x2*)&lds_g[1][0][grow][cp]
                         + *(const f32x2*)&lds_g[1][1][grow][cp] + bias2[1];
                f32x2 gg = *(const f32x2*)&lds_g[2][0][grow][cp]
                         + *(const f32x2*)&lds_g[2][1][grow][cp] + bias2[2];
                f32x2 go = *(const f32x2*)&lds_g[3][0][grow][cp]
                         + *(const f32x2*)&lds_g[3][1][grow][cp] + bias2[3];
                f32x2 cn, hn;
#pragma unroll
                for (int q = 0; q < 2; ++q) {
                    float si = 1.f / (1.f + __expf(-gi[q]));
                    float sf = 1.f / (1.f + __expf(-gf[q]));
                    float so = 1.f / (1.f + __expf(-go[q]));
                    float tg = tanh_fast(gg[q]);
                    cn[q] = sf * creg[q] + si * tg;
                    hn[q] = so * tanh_fast(cn[q]);
                }
                creg = cn;

                unsigned hp = (unsigned)f32_to_bf16(hn[0])
                            | ((unsigned)f32_to_bf16(hn[1]) << 16);
                u64 rec = (u64)hp | ((u64)(unsigned)(t + 1) << 32);
                u64* hw = ((layer == 0) ? h0T : h1T)
                        + (size_t)(t & 7) * (BATCH * RPR)
                        + (size_t)(quad * QR + grow) * RPR + ((j0 + cp) >> 1);
                __hip_atomic_store(hw, rec, __ATOMIC_RELAXED,
                                   __HIP_MEMORY_SCOPE_AGENT);

                // out / finals (plain stores, off the handshake path)
                const int hoff = (quad * QR + grow) * HID + j0 + cp;
                if (layer == 1)
                    *(f32x2*)&out[(size_t)t * BH + hoff] = hn;
                if (t == TSEQ - 1) {
                    size_t base = (size_t)TSEQ * BH + (size_t)layer * BH + hoff;
                    *(f32x2*)&out[base] = hn;                       // h_fin
                    *(f32x2*)&out[base + 2 * (size_t)BH] = cn;      // c_fin
                }
            }
        } else {
            // inactive stage: L1 keeps progress monotone for the throttle
            if (layer == 1 && tid == 0)
                __hip_atomic_store(myprog, s, __ATOMIC_RELAXED,
                                   __HIP_MEMORY_SCOPE_AGENT);
            __syncthreads();
        }
    }
}

extern "C" void kernel_launch(void* const* d_in, const int* in_sizes, int n_in,
                              void* d_out, int out_size, void* d_ws, size_t ws_size,
                              hipStream_t stream) {
    const float* x  = (const float*)d_in[0];
    const float* Wh = (const float*)d_in[1];
    const float* Wx = (const float*)d_in[2];
    const float* bh = (const float*)d_in[3];
    float* out = (float*)d_out;

    char* ws = (char*)d_ws;
    // layout: WT 8MB | xq 32MB | h0T 1MB | h1T 1MB | f1prog  (~42MB total)
    ushort* WT = (ushort*)ws;
    ushort* xq = (ushort*)(ws + ((size_t)8 << 20));
    char* state = ws + ((size_t)8 << 20) + ((size_t)32 << 20);
    u64* h0T = (u64*)state;                                // [8][64][256] u64
    u64* h1T = h0T + (size_t)DEPTH * BATCH * RPR;
    int* f1prog = (int*)(h1T + (size_t)DEPTH * BATCH * RPR);   // [4][16]
    size_t clear_bytes = (size_t)2 * DEPTH * BATCH * RPR * sizeof(u64)
                       + 64 * sizeof(int);

    hipMemsetAsync(state, 0, clear_bytes, stream);  // zero tags + progress flags
    convert_x<<<2048, 256, 0, stream>>>(x, xq);
    transpose_w<<<1024, 256, 0, stream>>>(Wh, Wx, WT);
    lstm_persistent<<<128, 1024, 0, stream>>>(WT, xq, bh, h0T, h1T, out, f1prog);
}